// Round 16
// baseline (209.434 us; speedup 1.0000x reference)
//
#include <hip/hip_runtime.h>
#include <stdint.h>

#define B_  16
#define L_  1024
#define D_  768

typedef unsigned short u16;
typedef __attribute__((ext_vector_type(4))) float f32x4;
typedef __attribute__((ext_vector_type(8))) _Float16 f16x8;

__device__ __forceinline__ u16 f2h(float x){
    return __builtin_bit_cast(u16, (_Float16)x);
}
__device__ __forceinline__ float h2f(u16 x){
    return (float)__builtin_bit_cast(_Float16, x);
}

__device__ __forceinline__ void gload_lds16(const void* g, void* l){
    __builtin_amdgcn_global_load_lds((const __attribute__((address_space(1))) void*)g,
                                     (__attribute__((address_space(3))) void*)l, 16, 0, 0);
}

// ---------------- prep (R14 grid): hH=h, wH=h+w2, B1=w1+q (fp16) + qT transpose; shared w1h,w2h ----------------
__global__ __launch_bounds__(256) void prep(const float* __restrict__ h, const float* __restrict__ q,
    const float* __restrict__ w1w, const float* __restrict__ w2w,
    u16* __restrict__ hH, u16* __restrict__ wH, u16* __restrict__ B1,
    u16* __restrict__ w1h, u16* __restrict__ w2h, u16* __restrict__ qT, int b0, int nb)
{
    __shared__ float tile[32][33];
    int bb = blockIdx.z, bg = b0 + bb;
    int t0 = blockIdx.x * 32, d0 = blockIdx.y * 32;
    int tid = threadIdx.x;
    int r  = tid >> 3;               // 0..31 (t row)
    int c4 = (tid & 7) * 4;          // 0..28 (d col, x4)
    int t = t0 + r, d = d0 + c4;
    size_t goff = (size_t)t * D_ + d;

    float4 qv  = *(const float4*)(q   + (size_t)bg * L_ * D_ + goff);
    float4 hv  = *(const float4*)(h   + (size_t)bg * L_ * D_ + goff);
    float4 w2v = *(const float4*)(w2w + goff);
    float4 w1v = *(const float4*)(w1w + goff);

    tile[r][c4 + 0] = qv.x; tile[r][c4 + 1] = qv.y;
    tile[r][c4 + 2] = qv.z; tile[r][c4 + 3] = qv.w;

    size_t o = ((size_t)bb * L_ + t) * D_ + d;
    ushort4 a;
    a.x = f2h(hv.x); a.y = f2h(hv.y); a.z = f2h(hv.z); a.w = f2h(hv.w);
    *(ushort4*)(hH + o) = a;
    a.x = f2h(hv.x + w2v.x); a.y = f2h(hv.y + w2v.y);
    a.z = f2h(hv.z + w2v.z); a.w = f2h(hv.w + w2v.w);
    *(ushort4*)(wH + o) = a;
    a.x = f2h(w1v.x + qv.x); a.y = f2h(w1v.y + qv.y);
    a.z = f2h(w1v.z + qv.z); a.w = f2h(w1v.w + qv.w);
    *(ushort4*)(B1 + o) = a;
    if (bb == 0){
        a.x = f2h(w1v.x); a.y = f2h(w1v.y); a.z = f2h(w1v.z); a.w = f2h(w1v.w);
        *(ushort4*)(w1h + goff) = a;
        a.x = f2h(w2v.x); a.y = f2h(w2v.y); a.z = f2h(w2v.z); a.w = f2h(w2v.w);
        *(ushort4*)(w2h + goff) = a;
    }
    __syncthreads();
    // transpose write: thread -> d-row (d0+dr), t-cols t0+tc..tc+3
    int dr = tid >> 3;               // 0..31
    int tc = (tid & 7) * 4;          // 0..28
    ushort4 b;
    b.x = f2h(tile[tc + 0][dr]); b.y = f2h(tile[tc + 1][dr]);
    b.z = f2h(tile[tc + 2][dr]); b.w = f2h(tile[tc + 3][dr]);
    *(ushort4*)(qT + (size_t)bb * D_ * L_ + (size_t)(d0 + dr) * L_ + t0 + tc) = b;
}

// ---------------- c0k: C0 = w2 @ w1^T (batch-invariant, 1024^2, K=768), 256^2 pipeline ----------------
__global__ __launch_bounds__(512) void c0k(const u16* __restrict__ w2h, const u16* __restrict__ w1h,
                                           float* __restrict__ C0)
{
    __shared__ u16 ldsA[2][256 * 64];
    __shared__ u16 ldsB[2][256 * 64];
    int tl = blockIdx.x;                             // 16 wg
    int smb = tl >> 2, tnb = tl & 3;
    int s0 = smb * 256, t0 = tnb * 256;
    int tid = threadIdx.x;
    int lane = tid & 63, wid = tid >> 6;
    int wm2 = wid >> 2, wn2 = wid & 3;
    int l15 = lane & 15, l4 = lane >> 4;

    f32x4 acc[8][4];
    #pragma unroll
    for (int m = 0; m < 8; m++)
        #pragma unroll
        for (int n = 0; n < 4; n++)
            acc[m][n] = (f32x4){0.f, 0.f, 0.f, 0.f};

    auto stage = [&](int t){
        int kb = t * 64;
        int buf = t & 1;
        #pragma unroll
        for (int q = 0; q < 4; q++){
            int idx = q * 512 + tid;
            int row = idx >> 3, c = idx & 7;
            int cc = c ^ (row & 7);
            int dst = (q * 512 + wid * 64) * 8;
            gload_lds16(w2h + (size_t)(s0 + row) * D_ + kb + cc * 8, &ldsA[buf][dst]);
            gload_lds16(w1h + (size_t)(t0 + row) * D_ + kb + cc * 8, &ldsB[buf][dst]);
        }
    };

    stage(0);
    asm volatile("s_waitcnt vmcnt(0)" ::: "memory");
    __builtin_amdgcn_s_barrier();

    for (int t = 0; t < 12; t++){
        if (t + 1 < 12) stage(t + 1);
        int bsel = t & 1;
        #pragma unroll
        for (int kk = 0; kk < 2; kk++){
            f16x8 bf[4];
            #pragma unroll
            for (int n = 0; n < 4; n++){
                int row = wn2 * 64 + n * 16 + l15;
                int c = kk * 4 + l4;
                bf[n] = *(const f16x8*)&ldsB[bsel][(row * 8 + (c ^ (row & 7))) * 8];
            }
            #pragma unroll
            for (int mh = 0; mh < 2; mh++){
                f16x8 af[4];
                #pragma unroll
                for (int mi = 0; mi < 4; mi++){
                    int row = wm2 * 128 + (mh * 4 + mi) * 16 + l15;
                    int c = kk * 4 + l4;
                    af[mi] = *(const f16x8*)&ldsA[bsel][(row * 8 + (c ^ (row & 7))) * 8];
                }
                #pragma unroll
                for (int mi = 0; mi < 4; mi++)
                    #pragma unroll
                    for (int n = 0; n < 4; n++)
                        acc[mh * 4 + mi][n] = __builtin_amdgcn_mfma_f32_16x16x32_f16(
                            af[mi], bf[n], acc[mh * 4 + mi][n], 0, 0, 0);
            }
        }
        asm volatile("s_waitcnt vmcnt(0)" ::: "memory");
        __builtin_amdgcn_s_barrier();
    }

    #pragma unroll
    for (int m = 0; m < 8; m++){
        int sbase = s0 + wm2 * 128 + m * 16 + l4 * 4;
        #pragma unroll
        for (int r = 0; r < 4; r++){
            int s = sbase + r;
            #pragma unroll
            for (int n = 0; n < 4; n++){
                int tcol = t0 + wn2 * 64 + n * 16 + l15;
                C0[(size_t)s * L_ + tcol] = acc[m][n][r];
            }
        }
    }
}

// ---------------- GEMM1 (K=768): a = wH @ B1^T - C0 + biases -> pT/mT/sT ----------------
__global__ __launch_bounds__(512) void gemm1(
    const u16* __restrict__ wH, const u16* __restrict__ B1,
    const float* __restrict__ w1b, const float* __restrict__ w2b,
    const float* __restrict__ C0,
    u16* __restrict__ pT, float* __restrict__ mT, float* __restrict__ sT)
{
    __shared__ u16 ldsA[2][256 * 64];
    __shared__ u16 ldsB[2][256 * 64];
    int nwg = gridDim.x;                             // 16*nb, always %8==0
    int o = blockIdx.x;
    int wg = (o & 7) * (nwg >> 3) + (o >> 3);        // XCD batch-grouping (bijective)
    int bb = wg >> 4;
    int tl = wg & 15;
    int smb = tl >> 2, tnb = tl & 3;
    int s0 = smb * 256, t0 = tnb * 256;
    int tid = threadIdx.x;
    int lane = tid & 63, wid = tid >> 6;
    int wm2 = wid >> 2, wn2 = wid & 3;
    int l15 = lane & 15, l4 = lane >> 4;

    const u16* Ab = wH + (size_t)bb * L_ * D_;
    const u16* Bb = B1 + (size_t)bb * L_ * D_;

    f32x4 acc[8][4];
    #pragma unroll
    for (int m = 0; m < 8; m++)
        #pragma unroll
        for (int n = 0; n < 4; n++)
            acc[m][n] = (f32x4){0.f, 0.f, 0.f, 0.f};

    auto stage = [&](int t){
        int kb = t * 64;
        int buf = t & 1;
        #pragma unroll
        for (int q = 0; q < 4; q++){
            int idx = q * 512 + tid;
            int row = idx >> 3, c = idx & 7;
            int cc = c ^ (row & 7);
            int dst = (q * 512 + wid * 64) * 8;
            gload_lds16(Ab + (size_t)(s0 + row) * D_ + kb + cc * 8, &ldsA[buf][dst]);
            gload_lds16(Bb + (size_t)(t0 + row) * D_ + kb + cc * 8, &ldsB[buf][dst]);
        }
    };

    stage(0);
    asm volatile("s_waitcnt vmcnt(0)" ::: "memory");
    __builtin_amdgcn_s_barrier();

    for (int t = 0; t < 12; t++){
        if (t + 1 < 12) stage(t + 1);
        int bsel = t & 1;
        #pragma unroll
        for (int kk = 0; kk < 2; kk++){
            f16x8 bf[4];
            #pragma unroll
            for (int n = 0; n < 4; n++){
                int row = wn2 * 64 + n * 16 + l15;
                int c = kk * 4 + l4;
                bf[n] = *(const f16x8*)&ldsB[bsel][(row * 8 + (c ^ (row & 7))) * 8];
            }
            #pragma unroll
            for (int mh = 0; mh < 2; mh++){
                f16x8 af[4];
                #pragma unroll
                for (int mi = 0; mi < 4; mi++){
                    int row = wm2 * 128 + (mh * 4 + mi) * 16 + l15;
                    int c = kk * 4 + l4;
                    af[mi] = *(const f16x8*)&ldsA[bsel][(row * 8 + (c ^ (row & 7))) * 8];
                }
                __builtin_amdgcn_s_setprio(1);
                #pragma unroll
                for (int mi = 0; mi < 4; mi++)
                    #pragma unroll
                    for (int n = 0; n < 4; n++)
                        acc[mh * 4 + mi][n] = __builtin_amdgcn_mfma_f32_16x16x32_f16(
                            af[mi], bf[n], acc[mh * 4 + mi][n], 0, 0, 0);
                __builtin_amdgcn_s_setprio(0);
            }
        }
        asm volatile("s_waitcnt vmcnt(0)" ::: "memory");
        __builtin_amdgcn_s_barrier();
    }

    u16* pRow = pT + (size_t)bb * L_ * L_;
    #pragma unroll
    for (int m = 0; m < 8; m++){
        #pragma unroll
        for (int r = 0; r < 4; r++){
            int s = s0 + wm2 * 128 + m * 16 + l4 * 4 + r;
            float w2v = w2b[s];
            const float* c0r = C0 + (size_t)s * L_;
            float v[4];
            float tmax = -1e30f;
            #pragma unroll
            for (int n = 0; n < 4; n++){
                int tcol = t0 + wn2 * 64 + n * 16 + l15;
                v[n] = acc[m][n][r] - c0r[tcol] + w1b[tcol] + w2v;
                tmax = fmaxf(tmax, v[n]);
            }
            #pragma unroll
            for (int o2 = 1; o2 < 16; o2 <<= 1)
                tmax = fmaxf(tmax, __shfl_xor(tmax, o2));
            float e[4];
            float gsum = 0.f;
            #pragma unroll
            for (int n = 0; n < 4; n++){
                e[n] = __expf(v[n] - tmax);          // f32-exact relative to true logits
                gsum += e[n];
            }
            #pragma unroll
            for (int n = 0; n < 4; n++){
                int tcol = t0 + wn2 * 64 + n * 16 + l15;
                pRow[(size_t)s * L_ + tcol] = f2h(e[n]);
            }
            #pragma unroll
            for (int o2 = 1; o2 < 16; o2 <<= 1)
                gsum += __shfl_xor(gsum, o2);
            if (l15 == 0){
                size_t mo = ((size_t)bb * L_ + s) * 16 + tnb * 4 + wn2;
                mT[mo] = tmax;
                sT[mo] = gsum;
            }
        }
    }
}

// ---------------- p2k: exact row max + p2 softmax + per-group scales sc[j][s] = exp(mT_j - m)/S ----------------
__global__ __launch_bounds__(1024) void p2k(const float* __restrict__ mT, const float* __restrict__ sT,
                                            float* __restrict__ p2, float* __restrict__ sc, int b0)
{
    __shared__ float red[16];
    int bb = blockIdx.x, bg = b0 + bb;
    int tid = threadIdx.x;                           // = s
    const float4* mv = (const float4*)(mT + ((size_t)bb * L_ + tid) * 16);
    float4 m0 = mv[0], m1 = mv[1], m2 = mv[2], m3 = mv[3];
    float mj[16] = {m0.x, m0.y, m0.z, m0.w, m1.x, m1.y, m1.z, m1.w,
                    m2.x, m2.y, m2.z, m2.w, m3.x, m3.y, m3.z, m3.w};
    float v = mj[0];
    #pragma unroll
    for (int i = 1; i < 16; i++) v = fmaxf(v, mj[i]);

    // p2 = softmax over s of v
    float mx = v;
    #pragma unroll
    for (int o = 32; o; o >>= 1) mx = fmaxf(mx, __shfl_xor(mx, o));
    if ((tid & 63) == 0) red[tid >> 6] = mx;
    __syncthreads();
    float m2g = red[0];
    #pragma unroll
    for (int i = 1; i < 16; i++) m2g = fmaxf(m2g, red[i]);
    float e = __expf(v - m2g);
    float sum = e;
    #pragma unroll
    for (int o = 32; o; o >>= 1) sum += __shfl_xor(sum, o);
    __syncthreads();
    if ((tid & 63) == 0) red[tid >> 6] = sum;
    __syncthreads();
    float st = 0.f;
    #pragma unroll
    for (int i = 0; i < 16; i++) st += red[i];
    p2[(size_t)bg * L_ + tid] = e / st;

    // per-group softmax scales
    const float4* sv = (const float4*)(sT + ((size_t)bb * L_ + tid) * 16);
    float4 s0v = sv[0], s1v = sv[1], s2v = sv[2], s3v = sv[3];
    float sj[16] = {s0v.x, s0v.y, s0v.z, s0v.w, s1v.x, s1v.y, s1v.z, s1v.w,
                    s2v.x, s2v.y, s2v.z, s2v.w, s3v.x, s3v.y, s3v.z, s3v.w};
    float ej[16];
    float S = 0.f;
    #pragma unroll
    for (int j = 0; j < 16; j++){
        ej[j] = __expf(mj[j] - v);
        S += sj[j] * ej[j];
    }
    float invS = 1.0f / S;
    float* scb = sc + (size_t)bb * 16 * L_;
    #pragma unroll
    for (int j = 0; j < 16; j++)
        scb[j * L_ + tid] = ej[j] * invS;            // coalesced per-j sweeps
}

// ---------------- GEMM2 (256x192 tile, 16 wg/batch = 1 wg/CU, deep pipeline) ----------------
// c = sum_j (sc[j][s]*pT_j) @ qT, write c into out c-section
__global__ __launch_bounds__(512) void gemm2(const u16* __restrict__ pT, const u16* __restrict__ qT,
    const float* __restrict__ sc, float* __restrict__ out, int b0)
{
    __shared__ u16 ldsA[2][256 * 64];                // 64 KB
    __shared__ u16 ldsB[2][192 * 64];                // 48 KB
    int nwg = gridDim.x;                             // 16*nb, %8==0
    int o = blockIdx.x;
    int wg = ((nwg & 7) == 0) ? ((o & 7) * (nwg >> 3) + (o >> 3)) : o;
    int bb = wg >> 4;
    int tl = wg & 15;
    int smb = tl >> 2, dnb = tl & 3;                 // 4 s-tiles x 4 d-tiles
    int s0 = smb * 256, d0 = dnb * 192;
    int tid = threadIdx.x;
    int lane = tid & 63, wid = tid >> 6;             // 8 waves
    int wm2 = wid >> 2, wn2 = wid & 3;               // 2M x 4N (per wave 128 x 48)
    int l15 = lane & 15, l4 = lane >> 4;

    const u16* Ab = pT + (size_t)bb * L_ * L_;
    const u16* Bb = qT + (size_t)bb * D_ * L_;
    const float* scb = sc + (size_t)bb * 16 * L_;

    f32x4 acc[8][3];
    #pragma unroll
    for (int m = 0; m < 8; m++)
        #pragma unroll
        for (int n = 0; n < 3; n++)
            acc[m][n] = (f32x4){0.f, 0.f, 0.f, 0.f};

    auto stage = [&](int t){
        int kb = t * 64;
        int buf = t & 1;
        #pragma unroll
        for (int qq = 0; qq < 4; qq++){              // A: 256 rows x 8 chunks = 2048
            int idx = qq * 512 + tid;
            int row = idx >> 3, c = idx & 7;
            int cc = c ^ (row & 7);
            gload_lds16(Ab + (size_t)(s0 + row) * L_ + kb + cc * 8,
                        &ldsA[buf][(qq * 512 + wid * 64) * 8]);
        }
        #pragma unroll
        for (int qq = 0; qq < 3; qq++){              // B: 192 rows x 8 chunks = 1536
            int idx = qq * 512 + tid;
            int row = idx >> 3, c = idx & 7;
            int cc = c ^ (row & 7);
            gload_lds16(Bb + (size_t)(d0 + row) * L_ + kb + cc * 8,
                        &ldsB[buf][(qq * 512 + wid * 64) * 8]);
        }
    };

    stage(0);
    asm volatile("s_waitcnt vmcnt(0)" ::: "memory");
    __builtin_amdgcn_s_barrier();

    for (int t = 0; t < 16; t++){
        if (t + 1 < 16) stage(t + 1);
        int bsel = t & 1;
        // per-row group scale for this K-tile (jg = t), fp16
        _Float16 sch[8];
        #pragma unroll
        for (int m = 0; m < 8; m++)
            sch[m] = (_Float16)scb[(size_t)t * L_ + s0 + wm2 * 128 + m * 16 + l15];
        #pragma unroll
        for (int kk = 0; kk < 2; kk++){
            f16x8 bf[3];
            #pragma unroll
            for (int n = 0; n < 3; n++){
                int row = wn2 * 48 + n * 16 + l15;
                int c = kk * 4 + l4;
                bf[n] = *(const f16x8*)&ldsB[bsel][(row * 8 + (c ^ (row & 7))) * 8];
            }
            #pragma unroll
            for (int mh = 0; mh < 2; mh++){
                f16x8 af[4];
                #pragma unroll
                for (int mi = 0; mi < 4; mi++){
                    int row = wm2 * 128 + (mh * 4 + mi) * 16 + l15;
                    int c = kk * 4 + l4;
                    af[mi] = *(const f16x8*)&ldsA[bsel][(row * 8 + (c ^ (row & 7))) * 8];
                    af[mi] = af[mi] * sch[mh * 4 + mi];   // fold sc[j][s] into A
                }
                __builtin_amdgcn_s_setprio(1);
                #pragma unroll
                for (int mi = 0; mi < 4; mi++)
                    #pragma unroll
                    for (int n = 0; n < 3; n++)
                        acc[mh * 4 + mi][n] = __builtin_amdgcn_mfma_f32_16x16x32_f16(
                            af[mi], bf[n], acc[mh * 4 + mi][n], 0, 0, 0);
                __builtin_amdgcn_s_setprio(0);
            }
        }
        asm volatile("s_waitcnt vmcnt(0)" ::: "memory");
        __builtin_amdgcn_s_barrier();
    }

    // write c directly into out[.., D..2D)
    float* oC = out + ((size_t)(b0 + bb) * L_) * (4 * D_) + D_;
    #pragma unroll
    for (int m = 0; m < 8; m++){
        int sbase = s0 + wm2 * 128 + m * 16 + l4 * 4;
        #pragma unroll
        for (int r = 0; r < 4; r++){
            int s = sbase + r;
            #pragma unroll
            for (int n = 0; n < 3; n++){
                int d = d0 + wn2 * 48 + n * 16 + l15;
                oC[(size_t)s * (4 * D_) + d] = acc[m][n][r];
            }
        }
    }
}

// ---------------- epilogue (R14): read c from out + hH (fp16), write h / h*c / p2*h*c ----------------
__global__ __launch_bounds__(192) void epi(const u16* __restrict__ hH,
    const float* __restrict__ p2, float* __restrict__ out, int b0)
{
    int rowid = blockIdx.x;                          // bb*1024 + s
    int bb = rowid >> 10, s = rowid & 1023;
    int bg = b0 + bb;
    float p2v = p2[(size_t)bg * L_ + s];
    const u16* hR = hH + ((size_t)bb * L_ + s) * D_;
    float* oR = out + ((size_t)bg * L_ + s) * (4 * D_);
    int d = threadIdx.x * 4;
    float4 cv = *(const float4*)(oR + D_ + d);
    ushort4 hu = *(const ushort4*)(hR + d);
    float4 hv = {h2f(hu.x), h2f(hu.y), h2f(hu.z), h2f(hu.w)};
    float4 hc = {hv.x * cv.x, hv.y * cv.y, hv.z * cv.z, hv.w * cv.w};
    float4 qc = {p2v * hc.x, p2v * hc.y, p2v * hc.z, p2v * hc.w};
    *(float4*)(oR + d)          = hv;
    *(float4*)(oR + 2 * D_ + d) = hc;
    *(float4*)(oR + 3 * D_ + d) = qc;
}

extern "C" void kernel_launch(void* const* d_in, const int* in_sizes, int n_in,
                              void* d_out, int out_size, void* d_ws, size_t ws_size,
                              hipStream_t stream)
{
    const float* h   = (const float*)d_in[0];
    const float* q   = (const float*)d_in[1];
    const float* w1w = (const float*)d_in[2];
    const float* w1b = (const float*)d_in[3];
    const float* w2w = (const float*)d_in[4];
    const float* w2b = (const float*)d_in[5];
    float* out = (float*)d_out;

    const size_t szPlane = (size_t)L_ * D_ * 2;      // one fp16 plane, 1.5 MiB
    const size_t szM     = (size_t)B_ * L_ * 4;
    const size_t szC0    = (size_t)L_ * L_ * 4;      // 4 MiB f32
    const size_t perB_pT = (size_t)L_ * L_ * 2;      // 2 MiB fp16 exp values
    const size_t perB_s  = (size_t)L_ * 16 * 4;      // 64 KiB sidecar (each of mT, sT, sc)
    // per batch: hH, wH, B1, qT (4 planes) + pT + mT + sT + sc
    const size_t perB = 4 * szPlane + perB_pT + 3 * perB_s;   // ~8.2 MiB
    const size_t fixed = 2 * szPlane + szC0 + szM;   // w1h + w2h + C0 + p2

    int NB = 1;
    if (ws_size > fixed){
        size_t nbc = (ws_size - fixed) / perB;
        NB = (nbc >= 16) ? 16 : (nbc < 1 ? 1 : (int)nbc);
    }

    char* p = (char*)d_ws;
    u16*   w1h  = (u16*)p;   p += szPlane;
    u16*   w2h  = (u16*)p;   p += szPlane;
    float* C0   = (float*)p; p += szC0;
    float* p2   = (float*)p; p += szM;
    float* mT   = (float*)p; p += perB_s * NB;
    float* sT   = (float*)p; p += perB_s * NB;
    float* sc   = (float*)p; p += perB_s * NB;
    u16*   hH   = (u16*)p;   p += szPlane * NB;
    u16*   wH   = (u16*)p;   p += szPlane * NB;
    u16*   B1   = (u16*)p;   p += szPlane * NB;
    u16*   qT   = (u16*)p;   p += szPlane * NB;
    u16*   pT   = (u16*)p;

    for (int b0 = 0; b0 < B_; b0 += NB){
        int nb = (B_ - b0 < NB) ? (B_ - b0) : NB;
        prep  <<<dim3(32, 24, nb), 256, 0, stream>>>(h, q, w1w, w2w, hH, wH, B1, w1h, w2h, qT, b0, nb);
        if (b0 == 0)
            c0k <<<dim3(16), 512, 0, stream>>>(w2h, w1h, C0);
        gemm1 <<<dim3(16 * nb), 512, 0, stream>>>(wH, B1, w1b, w2b, C0, pT, mT, sT);
        p2k   <<<dim3(nb), 1024, 0, stream>>>(mT, sT, p2, sc, b0);
        gemm2 <<<dim3(16 * nb), 512, 0, stream>>>(pT, qT, sc, out, b0);
        epi   <<<dim3(nb * 1024), 192, 0, stream>>>(hH, p2, out, b0);
    }
}

// Round 17
// 193.842 us; speedup vs baseline: 1.0804x; 1.0804x over previous
//
#include <hip/hip_runtime.h>
#include <stdint.h>

#define B_  16
#define L_  1024
#define D_  768
#define K1_ 1536

typedef unsigned short u16;
typedef __attribute__((ext_vector_type(4))) float f32x4;
typedef __attribute__((ext_vector_type(8))) _Float16 f16x8;

__device__ __forceinline__ u16 f2h(float x){
    return __builtin_bit_cast(u16, (_Float16)x);
}
__device__ __forceinline__ float h2f(u16 x){
    return (float)__builtin_bit_cast(_Float16, x);
}

__device__ __forceinline__ void gload_lds16(const void* g, void* l){
    __builtin_amdgcn_global_load_lds((const __attribute__((address_space(1))) void*)g,
                                     (__attribute__((address_space(3))) void*)l, 16, 0, 0);
}

// ---------------- prep (fused): planes hH=h, wH=h+w2, qH=q, w1h=w1 (all fp16) + qT transpose ----------------
__global__ __launch_bounds__(256) void prep(const float* __restrict__ h, const float* __restrict__ q,
    const float* __restrict__ w1w, const float* __restrict__ w2w,
    u16* __restrict__ hH, u16* __restrict__ wH, u16* __restrict__ qH,
    u16* __restrict__ w1h, u16* __restrict__ qT, int b0, int nb)
{
    __shared__ float tile[32][33];
    int bb = blockIdx.z, bg = b0 + bb;
    int t0 = blockIdx.x * 32, d0 = blockIdx.y * 32;
    int tid = threadIdx.x;
    int r  = tid >> 3;               // 0..31 (t row)
    int c4 = (tid & 7) * 4;          // 0..28 (d col, x4)
    int t = t0 + r, d = d0 + c4;
    size_t goff = (size_t)t * D_ + d;

    float4 qv  = *(const float4*)(q   + (size_t)bg * L_ * D_ + goff);
    float4 hv  = *(const float4*)(h   + (size_t)bg * L_ * D_ + goff);
    float4 w2v = *(const float4*)(w2w + goff);

    tile[r][c4 + 0] = qv.x; tile[r][c4 + 1] = qv.y;
    tile[r][c4 + 2] = qv.z; tile[r][c4 + 3] = qv.w;

    size_t o = ((size_t)bb * L_ + t) * D_ + d;
    ushort4 a;
    a.x = f2h(hv.x); a.y = f2h(hv.y); a.z = f2h(hv.z); a.w = f2h(hv.w);
    *(ushort4*)(hH + o) = a;
    a.x = f2h(hv.x + w2v.x); a.y = f2h(hv.y + w2v.y);
    a.z = f2h(hv.z + w2v.z); a.w = f2h(hv.w + w2v.w);
    *(ushort4*)(wH + o) = a;
    a.x = f2h(qv.x); a.y = f2h(qv.y); a.z = f2h(qv.z); a.w = f2h(qv.w);
    *(ushort4*)(qH + o) = a;
    if (bb == 0){
        float4 w1v = *(const float4*)(w1w + goff);
        a.x = f2h(w1v.x); a.y = f2h(w1v.y); a.z = f2h(w1v.z); a.w = f2h(w1v.w);
        *(ushort4*)(w1h + goff) = a;
    }
    __syncthreads();
    // transpose write: thread -> d-row (d0+dr), t-cols t0+tc..tc+3
    int dr = tid >> 3;               // 0..31
    int tc = (tid & 7) * 4;          // 0..28
    ushort4 b;
    b.x = f2h(tile[tc + 0][dr]); b.y = f2h(tile[tc + 1][dr]);
    b.z = f2h(tile[tc + 2][dr]); b.w = f2h(tile[tc + 3][dr]);
    *(ushort4*)(qT + (size_t)bb * D_ * L_ + (size_t)(d0 + dr) * L_ + t0 + tc) = b;
}

// ---------------- GEMM1 (256^2 tile, 8 waves, double-buffered deep pipeline) ----------------
// logits -> pT = fp16(exp(v - tmax)) + sidecars mT (64-col group max), sT (group sum)
__global__ __launch_bounds__(512) void gemm1(
    const u16* __restrict__ hH, const u16* __restrict__ wH,
    const u16* __restrict__ qH, const u16* __restrict__ w1h,
    const float* __restrict__ w1b, const float* __restrict__ w2b,
    u16* __restrict__ pT, float* __restrict__ mT, float* __restrict__ sT)
{
    __shared__ u16 ldsA[2][256 * 64];                // 64 KB
    __shared__ u16 ldsB[2][256 * 64];                // 64 KB
    int nwg = gridDim.x;                             // 16*nb, always %8==0
    int o = blockIdx.x;
    int wg = (o & 7) * (nwg >> 3) + (o >> 3);        // XCD batch-grouping (bijective)
    int bb = wg >> 4;
    int tl = wg & 15;
    int smb = tl >> 2, tnb = tl & 3;
    int s0 = smb * 256, t0 = tnb * 256;
    int tid = threadIdx.x;
    int lane = tid & 63, wid = tid >> 6;             // 8 waves
    int wm2 = wid >> 2, wn2 = wid & 3;               // 2M x 4N wave grid
    int l15 = lane & 15, l4 = lane >> 4;

    const u16* hHb = hH + (size_t)bb * L_ * D_;
    const u16* wHb = wH + (size_t)bb * L_ * D_;
    const u16* qHb = qH + (size_t)bb * L_ * D_;

    f32x4 acc[8][4];
    #pragma unroll
    for (int m = 0; m < 8; m++)
        #pragma unroll
        for (int n = 0; n < 4; n++)
            acc[m][n] = (f32x4){0.f, 0.f, 0.f, 0.f};

    // stage K-tile t into LDS buffer (t&1): 4 rounds x (1 A-load + 1 B-load) per thread
    auto stage = [&](int t){
        int kb = t * 64;
        bool inH = (kb < D_);
        const u16* As = inH ? hHb : wHb;             // A rows (s-indexed)
        const u16* Bs = inH ? w1h : qHb;             // B rows (t-indexed)
        int koff = inH ? kb : (kb - D_);
        int buf = t & 1;
        #pragma unroll
        for (int q = 0; q < 4; q++){
            int idx = q * 512 + tid;                 // chunk index 0..2047
            int row = idx >> 3, c = idx & 7;
            int cc = c ^ (row & 7);                  // pre-swizzled global chunk
            int dst = (q * 512 + wid * 64) * 8;      // wave-uniform base; HW adds lane*16B
            gload_lds16(As + (size_t)(s0 + row) * D_ + koff + cc * 8, &ldsA[buf][dst]);
            gload_lds16(Bs + (size_t)(t0 + row) * D_ + koff + cc * 8, &ldsB[buf][dst]);
        }
    };

    stage(0);
    asm volatile("s_waitcnt vmcnt(0)" ::: "memory");
    __builtin_amdgcn_s_barrier();

    for (int t = 0; t < 24; t++){
        if (t + 1 < 24) stage(t + 1);                // prefetch next tile into other buffer
        int bsel = t & 1;
        #pragma unroll
        for (int kk = 0; kk < 2; kk++){
            f16x8 bf[4];
            #pragma unroll
            for (int n = 0; n < 4; n++){
                int row = wn2 * 64 + n * 16 + l15;
                int c = kk * 4 + l4;
                bf[n] = *(const f16x8*)&ldsB[bsel][(row * 8 + (c ^ (row & 7))) * 8];
            }
            #pragma unroll
            for (int mh = 0; mh < 2; mh++){
                f16x8 af[4];
                #pragma unroll
                for (int mi = 0; mi < 4; mi++){
                    int row = wm2 * 128 + (mh * 4 + mi) * 16 + l15;
                    int c = kk * 4 + l4;
                    af[mi] = *(const f16x8*)&ldsA[bsel][(row * 8 + (c ^ (row & 7))) * 8];
                }
                __builtin_amdgcn_s_setprio(1);
                #pragma unroll
                for (int mi = 0; mi < 4; mi++)
                    #pragma unroll
                    for (int n = 0; n < 4; n++)
                        acc[mh * 4 + mi][n] = __builtin_amdgcn_mfma_f32_16x16x32_f16(
                            af[mi], bf[n], acc[mh * 4 + mi][n], 0, 0, 0);
                __builtin_amdgcn_s_setprio(0);
            }
        }
        // drain this wave's prefetch loads (issued ~64 MFMAs ago), then cross-wave barrier
        asm volatile("s_waitcnt vmcnt(0)" ::: "memory");
        __builtin_amdgcn_s_barrier();
    }

    u16* pRow = pT + (size_t)bb * L_ * L_;
    #pragma unroll
    for (int m = 0; m < 8; m++){
        #pragma unroll
        for (int r = 0; r < 4; r++){
            int s = s0 + wm2 * 128 + m * 16 + l4 * 4 + r;
            float w2v = w2b[s];
            float v[4];
            float tmax = -1e30f;
            #pragma unroll
            for (int n = 0; n < 4; n++){
                int tcol = t0 + wn2 * 64 + n * 16 + l15;
                v[n] = acc[m][n][r] + w1b[tcol] + w2v;
                tmax = fmaxf(tmax, v[n]);
            }
            #pragma unroll
            for (int o2 = 1; o2 < 16; o2 <<= 1)
                tmax = fmaxf(tmax, __shfl_xor(tmax, o2));
            float e[4];
            float gsum = 0.f;
            #pragma unroll
            for (int n = 0; n < 4; n++){
                e[n] = __expf(v[n] - tmax);          // f32-exact relative to true logits
                gsum += e[n];
            }
            #pragma unroll
            for (int n = 0; n < 4; n++){
                int tcol = t0 + wn2 * 64 + n * 16 + l15;
                pRow[(size_t)s * L_ + tcol] = f2h(e[n]);
            }
            #pragma unroll
            for (int o2 = 1; o2 < 16; o2 <<= 1)
                gsum += __shfl_xor(gsum, o2);
            if (l15 == 0){
                size_t mo = ((size_t)bb * L_ + s) * 16 + tnb * 4 + wn2;
                mT[mo] = tmax;
                sT[mo] = gsum;
            }
        }
    }
}

// ---------------- p2k: exact row max + p2 softmax + per-group scales sc[j][s] = exp(mT_j - m)/S ----------------
__global__ __launch_bounds__(1024) void p2k(const float* __restrict__ mT, const float* __restrict__ sT,
                                            float* __restrict__ p2, float* __restrict__ sc, int b0)
{
    __shared__ float red[16];
    int bb = blockIdx.x, bg = b0 + bb;
    int tid = threadIdx.x;                           // = s
    const float4* mv = (const float4*)(mT + ((size_t)bb * L_ + tid) * 16);
    float4 m0 = mv[0], m1 = mv[1], m2 = mv[2], m3 = mv[3];
    float mj[16] = {m0.x, m0.y, m0.z, m0.w, m1.x, m1.y, m1.z, m1.w,
                    m2.x, m2.y, m2.z, m2.w, m3.x, m3.y, m3.z, m3.w};
    float v = mj[0];
    #pragma unroll
    for (int i = 1; i < 16; i++) v = fmaxf(v, mj[i]);

    // p2 = softmax over s of v
    float mx = v;
    #pragma unroll
    for (int o = 32; o; o >>= 1) mx = fmaxf(mx, __shfl_xor(mx, o));
    if ((tid & 63) == 0) red[tid >> 6] = mx;
    __syncthreads();
    float m2g = red[0];
    #pragma unroll
    for (int i = 1; i < 16; i++) m2g = fmaxf(m2g, red[i]);
    float e = __expf(v - m2g);
    float sum = e;
    #pragma unroll
    for (int o = 32; o; o >>= 1) sum += __shfl_xor(sum, o);
    __syncthreads();
    if ((tid & 63) == 0) red[tid >> 6] = sum;
    __syncthreads();
    float st = 0.f;
    #pragma unroll
    for (int i = 0; i < 16; i++) st += red[i];
    p2[(size_t)bg * L_ + tid] = e / st;

    // per-group softmax scales
    const float4* sv = (const float4*)(sT + ((size_t)bb * L_ + tid) * 16);
    float4 s0v = sv[0], s1v = sv[1], s2v = sv[2], s3v = sv[3];
    float sj[16] = {s0v.x, s0v.y, s0v.z, s0v.w, s1v.x, s1v.y, s1v.z, s1v.w,
                    s2v.x, s2v.y, s2v.z, s2v.w, s3v.x, s3v.y, s3v.z, s3v.w};
    float ej[16];
    float S = 0.f;
    #pragma unroll
    for (int j = 0; j < 16; j++){
        ej[j] = __expf(mj[j] - v);
        S += sj[j] * ej[j];
    }
    float invS = 1.0f / S;
    float* scb = sc + (size_t)bb * 16 * L_;
    #pragma unroll
    for (int j = 0; j < 16; j++)
        scb[j * L_ + tid] = ej[j] * invS;            // coalesced per-j sweeps
}

// ---------------- GEMM2 (256x192 tile, 16 wg/batch = 1 wg/CU, deep pipeline) ----------------
// c = sum_j (sc[j][s]*pT_j) @ qT, write c into out c-section
__global__ __launch_bounds__(512) void gemm2(const u16* __restrict__ pT, const u16* __restrict__ qT,
    const float* __restrict__ sc, float* __restrict__ out, int b0)
{
    __shared__ u16 ldsA[2][256 * 64];                // 64 KB
    __shared__ u16 ldsB[2][192 * 64];                // 48 KB
    int nwg = gridDim.x;                             // 16*nb, %8==0
    int o = blockIdx.x;
    int wg = ((nwg & 7) == 0) ? ((o & 7) * (nwg >> 3) + (o >> 3)) : o;
    int bb = wg >> 4;
    int tl = wg & 15;
    int smb = tl >> 2, dnb = tl & 3;                 // 4 s-tiles x 4 d-tiles
    int s0 = smb * 256, d0 = dnb * 192;
    int tid = threadIdx.x;
    int lane = tid & 63, wid = tid >> 6;             // 8 waves
    int wm2 = wid >> 2, wn2 = wid & 3;               // 2M x 4N (per wave 128 x 48)
    int l15 = lane & 15, l4 = lane >> 4;

    const u16* Ab = pT + (size_t)bb * L_ * L_;
    const u16* Bb = qT + (size_t)bb * D_ * L_;
    const float* scb = sc + (size_t)bb * 16 * L_;

    f32x4 acc[8][3];
    #pragma unroll
    for (int m = 0; m < 8; m++)
        #pragma unroll
        for (int n = 0; n < 3; n++)
            acc[m][n] = (f32x4){0.f, 0.f, 0.f, 0.f};

    auto stage = [&](int t){
        int kb = t * 64;
        int buf = t & 1;
        #pragma unroll
        for (int qq = 0; qq < 4; qq++){              // A: 256 rows x 8 chunks = 2048
            int idx = qq * 512 + tid;
            int row = idx >> 3, c = idx & 7;
            int cc = c ^ (row & 7);
            gload_lds16(Ab + (size_t)(s0 + row) * L_ + kb + cc * 8,
                        &ldsA[buf][(qq * 512 + wid * 64) * 8]);
        }
        #pragma unroll
        for (int qq = 0; qq < 3; qq++){              // B: 192 rows x 8 chunks = 1536
            int idx = qq * 512 + tid;
            int row = idx >> 3, c = idx & 7;
            int cc = c ^ (row & 7);
            gload_lds16(Bb + (size_t)(d0 + row) * L_ + kb + cc * 8,
                        &ldsB[buf][(qq * 512 + wid * 64) * 8]);
        }
    };

    stage(0);
    asm volatile("s_waitcnt vmcnt(0)" ::: "memory");
    __builtin_amdgcn_s_barrier();

    for (int t = 0; t < 16; t++){
        if (t + 1 < 16) stage(t + 1);
        int bsel = t & 1;
        // per-row group scale for this K-tile (jg = t), fp16
        _Float16 sch[8];
        #pragma unroll
        for (int m = 0; m < 8; m++)
            sch[m] = (_Float16)scb[(size_t)t * L_ + s0 + wm2 * 128 + m * 16 + l15];
        #pragma unroll
        for (int kk = 0; kk < 2; kk++){
            f16x8 bf[3];
            #pragma unroll
            for (int n = 0; n < 3; n++){
                int row = wn2 * 48 + n * 16 + l15;
                int c = kk * 4 + l4;
                bf[n] = *(const f16x8*)&ldsB[bsel][(row * 8 + (c ^ (row & 7))) * 8];
            }
            #pragma unroll
            for (int mh = 0; mh < 2; mh++){
                f16x8 af[4];
                #pragma unroll
                for (int mi = 0; mi < 4; mi++){
                    int row = wm2 * 128 + (mh * 4 + mi) * 16 + l15;
                    int c = kk * 4 + l4;
                    af[mi] = *(const f16x8*)&ldsA[bsel][(row * 8 + (c ^ (row & 7))) * 8];
                    af[mi] = af[mi] * sch[mh * 4 + mi];   // fold sc[j][s] into A
                }
                __builtin_amdgcn_s_setprio(1);
                #pragma unroll
                for (int mi = 0; mi < 4; mi++)
                    #pragma unroll
                    for (int n = 0; n < 3; n++)
                        acc[mh * 4 + mi][n] = __builtin_amdgcn_mfma_f32_16x16x32_f16(
                            af[mi], bf[n], acc[mh * 4 + mi][n], 0, 0, 0);
                __builtin_amdgcn_s_setprio(0);
            }
        }
        asm volatile("s_waitcnt vmcnt(0)" ::: "memory");
        __builtin_amdgcn_s_barrier();
    }

    // write c directly into out[.., D..2D)
    float* oC = out + ((size_t)(b0 + bb) * L_) * (4 * D_) + D_;
    #pragma unroll
    for (int m = 0; m < 8; m++){
        int sbase = s0 + wm2 * 128 + m * 16 + l4 * 4;
        #pragma unroll
        for (int r = 0; r < 4; r++){
            int s = sbase + r;
            #pragma unroll
            for (int n = 0; n < 3; n++){
                int d = d0 + wn2 * 48 + n * 16 + l15;
                oC[(size_t)s * (4 * D_) + d] = acc[m][n][r];
            }
        }
    }
}

// ---------------- epilogue: read c from out + hH (fp16), write h / h*c / p2*h*c sections ----------------
__global__ __launch_bounds__(192) void epi(const u16* __restrict__ hH,
    const float* __restrict__ p2, float* __restrict__ out, int b0)
{
    int rowid = blockIdx.x;                          // bb*1024 + s
    int bb = rowid >> 10, s = rowid & 1023;
    int bg = b0 + bb;
    float p2v = p2[(size_t)bg * L_ + s];
    const u16* hR = hH + ((size_t)bb * L_ + s) * D_;
    float* oR = out + ((size_t)bg * L_ + s) * (4 * D_);
    int d = threadIdx.x * 4;
    float4 cv = *(const float4*)(oR + D_ + d);
    ushort4 hu = *(const ushort4*)(hR + d);
    float4 hv = {h2f(hu.x), h2f(hu.y), h2f(hu.z), h2f(hu.w)};
    float4 hc = {hv.x * cv.x, hv.y * cv.y, hv.z * cv.z, hv.w * cv.w};
    float4 qc = {p2v * hc.x, p2v * hc.y, p2v * hc.z, p2v * hc.w};
    *(float4*)(oR + d)          = hv;
    *(float4*)(oR + 2 * D_ + d) = hc;
    *(float4*)(oR + 3 * D_ + d) = qc;
}

extern "C" void kernel_launch(void* const* d_in, const int* in_sizes, int n_in,
                              void* d_out, int out_size, void* d_ws, size_t ws_size,
                              hipStream_t stream)
{
    const float* h   = (const float*)d_in[0];
    const float* q   = (const float*)d_in[1];
    const float* w1w = (const float*)d_in[2];
    const float* w1b = (const float*)d_in[3];
    const float* w2w = (const float*)d_in[4];
    const float* w2b = (const float*)d_in[5];
    float* out = (float*)d_out;

    const size_t szPlane = (size_t)L_ * D_ * 2;      // one fp16 plane, 1.5 MiB
    const size_t szM     = (size_t)B_ * L_ * 4;
    const size_t perB_pT = (size_t)L_ * L_ * 2;      // 2 MiB fp16 exp values
    const size_t perB_s  = (size_t)L_ * 16 * 4;      // 64 KiB sidecar (each of mT, sT, sc)
    // per batch: hH, wH, qH, qT (4 planes) + pT + mT + sT + sc
    const size_t perB = 4 * szPlane + perB_pT + 3 * perB_s;   // ~8.2 MiB
    const size_t fixed = szPlane + szM;              // w1h + p2

    int NB = 1;
    if (ws_size > fixed){
        size_t nbc = (ws_size - fixed) / perB;
        NB = (nbc >= 16) ? 16 : (nbc < 1 ? 1 : (int)nbc);
    }

    char* p = (char*)d_ws;
    u16*   w1h  = (u16*)p;   p += szPlane;
    float* p2   = (float*)p; p += szM;
    float* mT   = (float*)p; p += perB_s * NB;
    float* sT   = (float*)p; p += perB_s * NB;
    float* sc   = (float*)p; p += perB_s * NB;
    u16*   hH   = (u16*)p;   p += szPlane * NB;
    u16*   wH   = (u16*)p;   p += szPlane * NB;
    u16*   qH   = (u16*)p;   p += szPlane * NB;
    u16*   qT   = (u16*)p;   p += szPlane * NB;
    u16*   pT   = (u16*)p;

    for (int b0 = 0; b0 < B_; b0 += NB){
        int nb = (B_ - b0 < NB) ? (B_ - b0) : NB;
        prep  <<<dim3(32, 24, nb), 256, 0, stream>>>(h, q, w1w, w2w, hH, wH, qH, w1h, qT, b0, nb);
        gemm1 <<<dim3(16 * nb), 512, 0, stream>>>(hH, wH, qH, w1h, w1b, w2b, pT, mT, sT);
        p2k   <<<dim3(nb), 1024, 0, stream>>>(mT, sT, p2, sc, b0);
        gemm2 <<<dim3(16 * nb), 512, 0, stream>>>(pT, qT, sc, out, b0);
        epi   <<<dim3(nb * 1024), 192, 0, stream>>>(hH, p2, out, b0);
    }
}